// Round 2
// baseline (759.338 us; speedup 1.0000x reference)
//
#include <hip/hip_runtime.h>

// Fully fused RNN: T=1024, B=256, D=64, H=128, fp32 in/out.
// One persistent block per batch element (256 blocks, 512 threads = 8 waves):
//   waves 0-3 : fp32 VALU scan  h' = tanh(z_t + h Whh^T)
//   waves 4-5 : feat producer   z = tanh(x Wx^T+bx) Wih^T + (bih+bhh)
//               ** tri-split f16 MFMA (A and B hi/lo) -> ~fp32 accuracy **
//   waves 6-7 : out consumer    y = tanh(h Wh^T+bh) Wg^T + bg
//               ** weight-split f16 MFMA (B hi/lo) **
// R1 failed on precision only (absmax 1.37e-2 vs 1.09e-2): chained f16
// roundings amplified by the recurrence. Producer/consumer waves have 12+
// idle step-slots of 16, so the 2-3x MFMA cost of splitting is free.
// Time = 64 granules x 16 steps; ONE lgkm-only barrier per step (vmcnt never
// drained). Barriers per role: 5 prologue + 64*16 + 1 epilogue = 1030.

#define T_SEQ 1024
#define B_SZ  256
#define D_IN  64
#define H_DIM 128

typedef __attribute__((ext_vector_type(8))) _Float16 half8;
typedef __attribute__((ext_vector_type(4))) _Float16 half4;
typedef __attribute__((ext_vector_type(4))) float f32x4;

__device__ __forceinline__ float fast_tanh(float x) {
  float ax = __builtin_fabsf(x);
  float e  = __builtin_amdgcn_exp2f(ax * -2.8853900817779268f); // -2*log2(e)
  float r  = (1.0f - e) * __builtin_amdgcn_rcpf(1.0f + e);
  return __builtin_copysignf(r, x);
}

// barrier waiting ONLY lgkmcnt (LDS): vm=63, exp=7, lgkm=0 -> imm 0xC07F
__device__ __forceinline__ void barrier_lds_only() {
  __asm__ __volatile__("" ::: "memory");
  __builtin_amdgcn_s_waitcnt(0xC07F);
  __builtin_amdgcn_s_barrier();
  __asm__ __volatile__("" ::: "memory");
}

__device__ __forceinline__ half8 pack_h8(float4 a, float4 b) {
  half8 s = { (_Float16)a.x, (_Float16)a.y, (_Float16)a.z, (_Float16)a.w,
              (_Float16)b.x, (_Float16)b.y, (_Float16)b.z, (_Float16)b.w };
  return s;
}
__device__ __forceinline__ half4 cvt_h4(float4 a) {
  half4 s = { (_Float16)a.x, (_Float16)a.y, (_Float16)a.z, (_Float16)a.w };
  return s;
}
// split fp32x8 into f16 hi + f16 lo (residual) fragments
__device__ __forceinline__ void split_h8(float4 a, float4 b, half8& hi, half8& lo) {
  hi = pack_h8(a, b);
  float4 ra = { a.x - (float)hi[0], a.y - (float)hi[1],
                a.z - (float)hi[2], a.w - (float)hi[3] };
  float4 rb = { b.x - (float)hi[4], b.y - (float)hi[5],
                b.z - (float)hi[6], b.w - (float)hi[7] };
  lo = pack_h8(ra, rb);
}

// 8-way lane reduction over ks=tid&7, all on VALU pipe (no DS op).
__device__ __forceinline__ float add_xor1(float x) {
  int v = __builtin_amdgcn_mov_dpp(__float_as_int(x), 0xB1, 0xF, 0xF, true);
  return x + __int_as_float(v);
}
__device__ __forceinline__ float add_xor2(float x) {
  int v = __builtin_amdgcn_mov_dpp(__float_as_int(x), 0x4E, 0xF, 0xF, true);
  return x + __int_as_float(v);
}
__device__ __forceinline__ float add_mirror8(float x) {
  int v = __builtin_amdgcn_mov_dpp(__float_as_int(x), 0x141, 0xF, 0xF, true);
  return x + __int_as_float(v);
}
__device__ __forceinline__ float dot4(float4 w, float4 h) {
  return fmaf(w.x, h.x, fmaf(w.y, h.y, fmaf(w.z, h.z, w.w * h.w)));
}

__global__ __launch_bounds__(512) void k_fused(
    const float* __restrict__ x,   const float* __restrict__ Wx,
    const float* __restrict__ bx,  const float* __restrict__ Wih,
    const float* __restrict__ bih, const float* __restrict__ Whh,
    const float* __restrict__ bhh, const float* __restrict__ Wh,
    const float* __restrict__ bh,  const float* __restrict__ Wg,
    const float* __restrict__ bg,  float* __restrict__ y)
{
  // LDS: 1024+40960+17408+2*2304+2*4352+4352 = 77056 B
  __shared__ __align__(16) float    hbuf[2][H_DIM];        // scan h dbuf (fp32)
  __shared__ __align__(16) float    zringT[4][H_DIM][20];  // z ring, [j][t]
  __shared__ __align__(16) _Float16 hring[4][16][136];     // h ring f16, [t&15][j]
  __shared__ __align__(16) _Float16 xt_h[16][72];          // x hi
  __shared__ __align__(16) _Float16 xt_l[16][72];          // x lo
  __shared__ __align__(16) _Float16 fm_h[16][136];         // feat hi
  __shared__ __align__(16) _Float16 fm_l[16][136];         // feat lo
  __shared__ __align__(16) _Float16 tpm[16][136];          // consumer tanh exchange

  const int tid = threadIdx.x;
  const int b   = blockIdx.x;
  const int wv  = tid >> 6;

  if (wv < 4) {
    // ================= scan (waves 0-3, fp32 VALU) =================
    const int jg = tid >> 3, ks = tid & 7, k0 = ks * 16;
    const bool writer = (ks < 4);
    const int j_out = jg + (ks & 3) * 32;

    float4 w[4][4];
#pragma unroll
    for (int r = 0; r < 4; ++r) {
      const float4* wg = (const float4*)(Whh + (jg + r*32)*H_DIM + k0);
#pragma unroll
      for (int m = 0; m < 4; ++m) w[r][m] = wg[m];
    }
    if (tid < 128) hbuf[0][tid] = 0.f;
    else           hring[0][0][tid - 128] = (_Float16)0.f;  // h_0 = 0

    for (int i = 0; i < 5; ++i) barrier_lds_only();         // prologue

    for (int g = 0; g < 64; ++g) {
      float zbuf[16];
      if (writer) {
        const float* zp = &zringT[g & 3][j_out][0];
        const float4 z0 = *(const float4*)(zp + 0);
        const float4 z1 = *(const float4*)(zp + 4);
        const float4 z2 = *(const float4*)(zp + 8);
        const float4 z3 = *(const float4*)(zp + 12);
        zbuf[0]=z0.x;  zbuf[1]=z0.y;  zbuf[2]=z0.z;  zbuf[3]=z0.w;
        zbuf[4]=z1.x;  zbuf[5]=z1.y;  zbuf[6]=z1.z;  zbuf[7]=z1.w;
        zbuf[8]=z2.x;  zbuf[9]=z2.y;  zbuf[10]=z2.z; zbuf[11]=z2.w;
        zbuf[12]=z3.x; zbuf[13]=z3.y; zbuf[14]=z3.z; zbuf[15]=z3.w;
      }
#pragma unroll
      for (int s = 0; s < 16; ++s) {
        const float* h = hbuf[s & 1];
        float4 h0 = *(const float4*)&h[k0];
        float4 h1 = *(const float4*)&h[k0 + 4];
        float4 h2 = *(const float4*)&h[k0 + 8];
        float4 h3 = *(const float4*)&h[k0 + 12];

        float a[4];
#pragma unroll
        for (int r = 0; r < 4; ++r) {
          float p0 = dot4(w[r][0], h0);
          float p1 = dot4(w[r][1], h1);
          float p2 = dot4(w[r][2], h2);
          float p3 = dot4(w[r][3], h3);
          a[r] = (p0 + p1) + (p2 + p3);
        }
#pragma unroll
        for (int r = 0; r < 4; ++r) {
          a[r] = add_xor1(a[r]);
          a[r] = add_xor2(a[r]);
          a[r] = add_mirror8(a[r]);
        }
        if (writer) {
          float v  = a[ks] + zbuf[s];
          float hn = fast_tanh(v);
          hbuf[(s & 1) ^ 1][j_out] = hn;
          const int tn = g*16 + s + 1;
          hring[(tn >> 4) & 3][tn & 15][j_out] = (_Float16)hn;
        }
        barrier_lds_only();
      }
    }
    barrier_lds_only();                                      // epilogue

  } else if (wv < 6) {
    // ===== feat producer (waves 4-5, tri-split f16 MFMA) =====
    const int l = tid & 63, ln = l & 15, kg = l >> 4;
    const int pw = wv - 4;
    const int xr0 = pw*8 + kg;

    half8 wxh[4][2], wxl[4][2];          // Wx hi/lo resident (64 VGPR)
    float bxr[4], b2r[4];
#pragma unroll
    for (int nt = 0; nt < 4; ++nt) {
      const int ro = (pw*4 + nt)*16 + ln;
#pragma unroll
      for (int kf = 0; kf < 2; ++kf) {
        const float* wp = Wx + ro*D_IN + kf*32 + kg*8;
        split_h8(*(const float4*)wp, *(const float4*)(wp + 4),
                 wxh[nt][kf], wxl[nt][kf]);
      }
      bxr[nt] = bx[ro];
      b2r[nt] = bih[ro] + bhh[ro];
    }

    float4 xa0, xa1;
    auto loadx = [&](int t0) {
      xa0 = *(const float4*)(x + ((long)(t0 + xr0    )*B_SZ + b)*D_IN + ln*4);
      xa1 = *(const float4*)(x + ((long)(t0 + xr0 + 4)*B_SZ + b)*D_IN + ln*4);
    };
    auto cvtx = [&]() {
      half4 h0 = cvt_h4(xa0);
      float4 r0 = { xa0.x - (float)h0[0], xa0.y - (float)h0[1],
                    xa0.z - (float)h0[2], xa0.w - (float)h0[3] };
      *(half4*)&xt_h[xr0][ln*4] = h0;
      *(half4*)&xt_l[xr0][ln*4] = cvt_h4(r0);
      half4 h1 = cvt_h4(xa1);
      float4 r1 = { xa1.x - (float)h1[0], xa1.y - (float)h1[1],
                    xa1.z - (float)h1[2], xa1.w - (float)h1[3] };
      *(half4*)&xt_h[xr0 + 4][ln*4] = h1;
      *(half4*)&xt_l[xr0 + 4][ln*4] = cvt_h4(r1);
    };
    auto stage1 = [&]() {                // feat = tanh(x Wx^T + bx), tri-split
      half8 a1h[2], a1l[2];
#pragma unroll
      for (int kf = 0; kf < 2; ++kf) {
        a1h[kf] = *(const half8*)&xt_h[ln][kf*32 + kg*8];
        a1l[kf] = *(const half8*)&xt_l[ln][kf*32 + kg*8];
      }
#pragma unroll
      for (int nt = 0; nt < 4; ++nt) {
        f32x4 acc = {0.f, 0.f, 0.f, 0.f};
#pragma unroll
        for (int kf = 0; kf < 2; ++kf) {
          acc = __builtin_amdgcn_mfma_f32_16x16x32_f16(a1h[kf], wxh[nt][kf], acc, 0, 0, 0);
          acc = __builtin_amdgcn_mfma_f32_16x16x32_f16(a1l[kf], wxh[nt][kf], acc, 0, 0, 0);
          acc = __builtin_amdgcn_mfma_f32_16x16x32_f16(a1h[kf], wxl[nt][kf], acc, 0, 0, 0);
        }
#pragma unroll
        for (int c = 0; c < 4; ++c) {
          float v = fast_tanh(acc[c] + bxr[nt]);
          _Float16 vh = (_Float16)v;
          fm_h[kg*4 + c][(pw*4 + nt)*16 + ln] = vh;
          fm_l[kg*4 + c][(pw*4 + nt)*16 + ln] = (_Float16)(v - (float)vh);
        }
      }
    };
    // z = feat Wih^T + b2, tri-split; Wih split transiently from L2 each use
    auto stage2_half = [&](int slot, int nt0) {
      half8 a2h[4], a2l[4];
#pragma unroll
      for (int kf = 0; kf < 4; ++kf) {
        a2h[kf] = *(const half8*)&fm_h[ln][kf*32 + kg*8];
        a2l[kf] = *(const half8*)&fm_l[ln][kf*32 + kg*8];
      }
#pragma unroll
      for (int nt = nt0; nt < nt0 + 2; ++nt) {
        const int ro = (pw*4 + nt)*16 + ln;
        f32x4 acc = { b2r[nt], b2r[nt], b2r[nt], b2r[nt] };
#pragma unroll
        for (int kf = 0; kf < 4; ++kf) {
          const float* wp = Wih + ro*H_DIM + kf*32 + kg*8;
          half8 bh_, bl_;
          split_h8(*(const float4*)wp, *(const float4*)(wp + 4), bh_, bl_);
          acc = __builtin_amdgcn_mfma_f32_16x16x32_f16(a2h[kf], bh_, acc, 0, 0, 0);
          acc = __builtin_amdgcn_mfma_f32_16x16x32_f16(a2l[kf], bh_, acc, 0, 0, 0);
          acc = __builtin_amdgcn_mfma_f32_16x16x32_f16(a2h[kf], bl_, acc, 0, 0, 0);
        }
        *(f32x4*)&zringT[slot][(pw*4 + nt)*16 + ln][kg*4] = acc;
      }
    };

    // prologue: granules 0 and 1 (5 barriers)
    loadx(0);
    cvtx(); loadx(16);            barrier_lds_only();   // B1
    stage1();                     barrier_lds_only();   // B2
    stage2_half(0, 0); stage2_half(0, 2);
    cvtx(); loadx(32);            barrier_lds_only();   // B3
    stage1();                     barrier_lds_only();   // B4
    stage2_half(1, 0); stage2_half(1, 2);
                                  barrier_lds_only();   // B5

    for (int g = 0; g < 64; ++g) {               // produce granule g+2 (g<=61)
      if (g <= 61) { cvtx(); if (g <= 60) loadx((g + 3) * 16); }
      barrier_lds_only();                        // s=0
      if (g <= 61) stage1();
      barrier_lds_only();                        // s=1
      if (g <= 61) stage2_half((g + 2) & 3, 0);
      barrier_lds_only();                        // s=2
      if (g <= 61) stage2_half((g + 2) & 3, 2);
      barrier_lds_only();                        // s=3
      for (int s = 4; s < 16; ++s) barrier_lds_only();
    }
    barrier_lds_only();                          // epilogue

  } else {
    // ===== out consumer (waves 6-7, weight-split f16 MFMA) =====
    const int l = tid & 63, ln = l & 15, kg = l >> 4;
    const int cw = wv - 6;

    float bhr[4], bgr[2];
#pragma unroll
    for (int nt = 0; nt < 4; ++nt) bhr[nt] = bh[(cw*4 + nt)*16 + ln];
#pragma unroll
    for (int n2 = 0; n2 < 2; ++n2) bgr[n2] = bg[(cw*2 + n2)*16 + ln];

    auto cstage1_half = [&](int slot, int nt0) { // tmp = tanh(h Wh^T + bh)
      half8 ah[4];
#pragma unroll
      for (int kf = 0; kf < 4; ++kf)
        ah[kf] = *(const half8*)&hring[slot][ln][kf*32 + kg*8];
#pragma unroll
      for (int nt = nt0; nt < nt0 + 2; ++nt) {
        const int ro = (cw*4 + nt)*16 + ln;
        f32x4 acc = {0.f, 0.f, 0.f, 0.f};
#pragma unroll
        for (int kf = 0; kf < 4; ++kf) {
          const float* wp = Wh + ro*H_DIM + kf*32 + kg*8;
          half8 bh_, bl_;
          split_h8(*(const float4*)wp, *(const float4*)(wp + 4), bh_, bl_);
          acc = __builtin_amdgcn_mfma_f32_16x16x32_f16(ah[kf], bh_, acc, 0, 0, 0);
          acc = __builtin_amdgcn_mfma_f32_16x16x32_f16(ah[kf], bl_, acc, 0, 0, 0);
        }
#pragma unroll
        for (int c = 0; c < 4; ++c)
          tpm[kg*4 + c][(cw*4 + nt)*16 + ln] =
              (_Float16)fast_tanh(acc[c] + bhr[nt]);
      }
    };
    auto cstage2 = [&](int t0) {                 // y = tmp Wg^T + bg
      half8 a2[4];
#pragma unroll
      for (int kf = 0; kf < 4; ++kf)
        a2[kf] = *(const half8*)&tpm[ln][kf*32 + kg*8];
#pragma unroll
      for (int n2 = 0; n2 < 2; ++n2) {
        const int ro = (cw*2 + n2)*16 + ln;
        f32x4 acc = { bgr[n2], bgr[n2], bgr[n2], bgr[n2] };
#pragma unroll
        for (int kf = 0; kf < 4; ++kf) {
          const float* wp = Wg + ro*H_DIM + kf*32 + kg*8;
          half8 bh_, bl_;
          split_h8(*(const float4*)wp, *(const float4*)(wp + 4), bh_, bl_);
          acc = __builtin_amdgcn_mfma_f32_16x16x32_f16(a2[kf], bh_, acc, 0, 0, 0);
          acc = __builtin_amdgcn_mfma_f32_16x16x32_f16(a2[kf], bl_, acc, 0, 0, 0);
        }
#pragma unroll
        for (int c = 0; c < 4; ++c)
          y[((long)(t0 + kg*4 + c)*B_SZ + b)*D_IN + (cw*2 + n2)*16 + ln] = acc[c];
      }
    };

    for (int i = 0; i < 5; ++i) barrier_lds_only();        // prologue

    for (int g = 0; g < 64; ++g) {               // consume granule g-1 (g>=1)
      barrier_lds_only();                        // s=0
      barrier_lds_only();                        // s=1
      if (g >= 1) cstage1_half((g - 1) & 3, 0);
      barrier_lds_only();                        // s=2
      if (g >= 1) cstage1_half((g - 1) & 3, 2);
      barrier_lds_only();                        // s=3
      if (g >= 1) cstage2((g - 1) * 16);
      barrier_lds_only();                        // s=4
      barrier_lds_only();                        // s=5
      for (int s = 6; s < 16; ++s) barrier_lds_only();
    }
    // epilogue: granule 63
    cstage1_half(3, 0);
    cstage1_half(3, 2);
    barrier_lds_only();
    cstage2(63 * 16);
  }
}

extern "C" void kernel_launch(void* const* d_in, const int* in_sizes, int n_in,
                              void* d_out, int out_size, void* d_ws, size_t ws_size,
                              hipStream_t stream) {
  const float* x   = (const float*)d_in[0];
  const float* Wx  = (const float*)d_in[1];
  const float* bx  = (const float*)d_in[2];
  const float* Wih = (const float*)d_in[3];
  const float* bih = (const float*)d_in[4];
  const float* Whh = (const float*)d_in[5];
  const float* bhh = (const float*)d_in[6];
  const float* Wh  = (const float*)d_in[7];
  const float* bh  = (const float*)d_in[8];
  const float* Wg  = (const float*)d_in[9];
  const float* bg  = (const float*)d_in[10];
  float* y = (float*)d_out;

  k_fused<<<B_SZ, 512, 0, stream>>>(x, Wx, bx, Wih, bih, Whh, bhh,
                                    Wh, bh, Wg, bg, y);
}

// Round 4
// 655.522 us; speedup vs baseline: 1.1584x; 1.1584x over previous
//
#include <hip/hip_runtime.h>

// Fully fused RNN: T=1024, B=256, D=64, H=128, fp32 in/out.
// One persistent block per batch element (256 blocks, 512 threads = 8 waves):
//   waves 0-3 : fp32 VALU scan  h' = tanh(z_t + h Whh^T)  [prio 1]
//   waves 4-5 : feat producer   z = tanh(x Wx^T+bx) Wih^T + (bih+bhh)
//               tri-split f16 MFMA (A and B hi/lo), R2-bit-exact arithmetic
//   waves 6-7 : out consumer    y = tanh(h Wh^T+bh) Wg^T + bg
//               weight-split f16 MFMA, R2-bit-exact arithmetic
// vs R2 (714us, passed 1.95e-3): NUMERICS UNCHANGED (R3's pre-split staging
// regressed accuracy and is reverted). Perf-only changes:
//  - weight loads issued one barrier-interval before use (hides L2 latency;
//    the barrier asm's memory clobber pins loads to their textual slot)
//  - heavy phases spread across slots (st1@#2, use2@#3/#4; usec1@#8/#9,
//    usec2@#11) so no slot exceeds ~400cy
//  - hbuf padded k+(k>>4)*8: kills 4-way bank conflict on scan's h read
//  - scan waves at s_setprio(1)
// Time = 64 granules x 16 steps; ONE lgkm-only barrier per step (vmcnt never
// drained). Barriers per role: 5 prologue + 64*16 + 1 epilogue = 1030.

#define T_SEQ 1024
#define B_SZ  256
#define D_IN  64
#define H_DIM 128

typedef __attribute__((ext_vector_type(8))) _Float16 half8;
typedef __attribute__((ext_vector_type(4))) _Float16 half4;
typedef __attribute__((ext_vector_type(4))) float f32x4;

__device__ __forceinline__ float fast_tanh(float x) {
  float ax = __builtin_fabsf(x);
  float e  = __builtin_amdgcn_exp2f(ax * -2.8853900817779268f); // -2*log2(e)
  float r  = (1.0f - e) * __builtin_amdgcn_rcpf(1.0f + e);
  return __builtin_copysignf(r, x);
}

// barrier waiting ONLY lgkmcnt (LDS): vm=63, exp=7, lgkm=0 -> imm 0xC07F
__device__ __forceinline__ void barrier_lds_only() {
  __asm__ __volatile__("" ::: "memory");
  __builtin_amdgcn_s_waitcnt(0xC07F);
  __builtin_amdgcn_s_barrier();
  __asm__ __volatile__("" ::: "memory");
}

__device__ __forceinline__ half8 pack_h8(float4 a, float4 b) {
  half8 s = { (_Float16)a.x, (_Float16)a.y, (_Float16)a.z, (_Float16)a.w,
              (_Float16)b.x, (_Float16)b.y, (_Float16)b.z, (_Float16)b.w };
  return s;
}
__device__ __forceinline__ half4 cvt_h4(float4 a) {
  half4 s = { (_Float16)a.x, (_Float16)a.y, (_Float16)a.z, (_Float16)a.w };
  return s;
}
// split fp32x8 into f16 hi + f16 lo (residual) fragments
__device__ __forceinline__ void split_h8(float4 a, float4 b, half8& hi, half8& lo) {
  hi = pack_h8(a, b);
  float4 ra = { a.x - (float)hi[0], a.y - (float)hi[1],
                a.z - (float)hi[2], a.w - (float)hi[3] };
  float4 rb = { b.x - (float)hi[4], b.y - (float)hi[5],
                b.z - (float)hi[6], b.w - (float)hi[7] };
  lo = pack_h8(ra, rb);
}

// 8-way lane reduction over ks=tid&7, all on VALU pipe (no DS op).
__device__ __forceinline__ float add_xor1(float x) {
  int v = __builtin_amdgcn_mov_dpp(__float_as_int(x), 0xB1, 0xF, 0xF, true);
  return x + __int_as_float(v);
}
__device__ __forceinline__ float add_xor2(float x) {
  int v = __builtin_amdgcn_mov_dpp(__float_as_int(x), 0x4E, 0xF, 0xF, true);
  return x + __int_as_float(v);
}
__device__ __forceinline__ float add_mirror8(float x) {
  int v = __builtin_amdgcn_mov_dpp(__float_as_int(x), 0x141, 0xF, 0xF, true);
  return x + __int_as_float(v);
}
__device__ __forceinline__ float dot4(float4 w, float4 h) {
  return fmaf(w.x, h.x, fmaf(w.y, h.y, fmaf(w.z, h.z, w.w * h.w)));
}

__global__ __launch_bounds__(512) void k_fused(
    const float* __restrict__ x,   const float* __restrict__ Wx,
    const float* __restrict__ bx,  const float* __restrict__ Wih,
    const float* __restrict__ bih, const float* __restrict__ Whh,
    const float* __restrict__ bhh, const float* __restrict__ Wh,
    const float* __restrict__ bh,  const float* __restrict__ Wg,
    const float* __restrict__ bg,  float* __restrict__ y)
{
  // LDS total = 1536+40960+17408+2*2304+2*4352+4352 = 77568 B
  __shared__ __align__(16) float    hbuf[2][192];          // padded: idx k+(k>>4)*8
  __shared__ __align__(16) float    zringT[4][H_DIM][20];  // z ring, [j][t]
  __shared__ __align__(16) _Float16 hring[4][16][136];     // h ring f16, [t&15][j]
  __shared__ __align__(16) _Float16 xt_h[16][72];          // x hi
  __shared__ __align__(16) _Float16 xt_l[16][72];          // x lo
  __shared__ __align__(16) _Float16 fm_h[16][136];         // feat hi
  __shared__ __align__(16) _Float16 fm_l[16][136];         // feat lo
  __shared__ __align__(16) _Float16 tpm[16][136];          // consumer tanh exchange

  const int tid = threadIdx.x;
  const int b   = blockIdx.x;
  const int wv  = tid >> 6;

  if (wv < 4) {
    // ================= scan (waves 0-3, fp32 VALU, prio 1) =================
    const int jg = tid >> 3, ks = tid & 7, k0p = ks * 24;  // padded base
    const bool writer = (ks < 4);
    const int j_out = jg + (ks & 3) * 32;
    const int j_pad = j_out + ((j_out >> 4) << 3);         // padded write idx

    float4 w[4][4];
#pragma unroll
    for (int r = 0; r < 4; ++r) {
      const float4* wg = (const float4*)(Whh + (jg + r*32)*H_DIM + ks*16);
#pragma unroll
      for (int m = 0; m < 4; ++m) w[r][m] = wg[m];
    }
    if (tid < 128) hbuf[0][tid + ((tid >> 4) << 3)] = 0.f;
    else           hring[0][0][tid - 128] = (_Float16)0.f;  // h_0 = 0

    __builtin_amdgcn_s_setprio(1);
    for (int i = 0; i < 5; ++i) barrier_lds_only();         // prologue

    for (int g = 0; g < 64; ++g) {
      float zbuf[16];
      if (writer) {
        const float* zp = &zringT[g & 3][j_out][0];
        const float4 z0 = *(const float4*)(zp + 0);
        const float4 z1 = *(const float4*)(zp + 4);
        const float4 z2 = *(const float4*)(zp + 8);
        const float4 z3 = *(const float4*)(zp + 12);
        zbuf[0]=z0.x;  zbuf[1]=z0.y;  zbuf[2]=z0.z;  zbuf[3]=z0.w;
        zbuf[4]=z1.x;  zbuf[5]=z1.y;  zbuf[6]=z1.z;  zbuf[7]=z1.w;
        zbuf[8]=z2.x;  zbuf[9]=z2.y;  zbuf[10]=z2.z; zbuf[11]=z2.w;
        zbuf[12]=z3.x; zbuf[13]=z3.y; zbuf[14]=z3.z; zbuf[15]=z3.w;
      }
#pragma unroll
      for (int s = 0; s < 16; ++s) {
        const float* h = hbuf[s & 1];
        float4 h0 = *(const float4*)&h[k0p];
        float4 h1 = *(const float4*)&h[k0p + 4];
        float4 h2 = *(const float4*)&h[k0p + 8];
        float4 h3 = *(const float4*)&h[k0p + 12];

        float a[4];
#pragma unroll
        for (int r = 0; r < 4; ++r) {
          float p0 = dot4(w[r][0], h0);
          float p1 = dot4(w[r][1], h1);
          float p2 = dot4(w[r][2], h2);
          float p3 = dot4(w[r][3], h3);
          a[r] = (p0 + p1) + (p2 + p3);
        }
#pragma unroll
        for (int r = 0; r < 4; ++r) {
          a[r] = add_xor1(a[r]);
          a[r] = add_xor2(a[r]);
          a[r] = add_mirror8(a[r]);
        }
        if (writer) {
          float v  = a[ks] + zbuf[s];
          float hn = fast_tanh(v);
          hbuf[(s & 1) ^ 1][j_pad] = hn;
          const int tn = g*16 + s + 1;
          hring[(tn >> 4) & 3][tn & 15][j_out] = (_Float16)hn;
        }
        barrier_lds_only();
      }
    }
    barrier_lds_only();                                      // epilogue

  } else if (wv < 6) {
    // ===== feat producer (waves 4-5, tri-split f16 MFMA, R2 numerics) =====
    const int l = tid & 63, ln = l & 15, kg = l >> 4;
    const int pw = wv - 4;
    const int xr0 = pw*8 + kg;

    half8 wxh[4][2], wxl[4][2];          // Wx hi/lo resident (64 VGPR)
    float bxr[4], b2r[4];
#pragma unroll
    for (int nt = 0; nt < 4; ++nt) {
      const int ro = (pw*4 + nt)*16 + ln;
#pragma unroll
      for (int kf = 0; kf < 2; ++kf) {
        const float* wp = Wx + ro*D_IN + kf*32 + kg*8;
        split_h8(*(const float4*)wp, *(const float4*)(wp + 4),
                 wxh[nt][kf], wxl[nt][kf]);
      }
      bxr[nt] = bx[ro];
      b2r[nt] = bih[ro] + bhh[ro];
    }

    float4 xa0, xa1;
    float4 lw[16];                       // prefetched Wih fp32 (64 VGPR)

    auto loadx = [&](int t0) {
      xa0 = *(const float4*)(x + ((long)(t0 + xr0    )*B_SZ + b)*D_IN + ln*4);
      xa1 = *(const float4*)(x + ((long)(t0 + xr0 + 4)*B_SZ + b)*D_IN + ln*4);
    };
    auto cvtx = [&]() {
      half4 h0 = cvt_h4(xa0);
      float4 r0 = { xa0.x - (float)h0[0], xa0.y - (float)h0[1],
                    xa0.z - (float)h0[2], xa0.w - (float)h0[3] };
      *(half4*)&xt_h[xr0][ln*4] = h0;
      *(half4*)&xt_l[xr0][ln*4] = cvt_h4(r0);
      half4 h1 = cvt_h4(xa1);
      float4 r1 = { xa1.x - (float)h1[0], xa1.y - (float)h1[1],
                    xa1.z - (float)h1[2], xa1.w - (float)h1[3] };
      *(half4*)&xt_h[xr0 + 4][ln*4] = h1;
      *(half4*)&xt_l[xr0 + 4][ln*4] = cvt_h4(r1);
    };
    // stage1: feat = tanh(x Wx^T + bx), tri-split (R2-exact)
    auto st1 = [&]() {
      half8 a1h[2], a1l[2];
#pragma unroll
      for (int kf = 0; kf < 2; ++kf) {
        a1h[kf] = *(const half8*)&xt_h[ln][kf*32 + kg*8];
        a1l[kf] = *(const half8*)&xt_l[ln][kf*32 + kg*8];
      }
#pragma unroll
      for (int nt = 0; nt < 4; ++nt) {
        f32x4 acc = {0.f, 0.f, 0.f, 0.f};
#pragma unroll
        for (int kf = 0; kf < 2; ++kf) {
          acc = __builtin_amdgcn_mfma_f32_16x16x32_f16(a1h[kf], wxh[nt][kf], acc, 0, 0, 0);
          acc = __builtin_amdgcn_mfma_f32_16x16x32_f16(a1l[kf], wxh[nt][kf], acc, 0, 0, 0);
          acc = __builtin_amdgcn_mfma_f32_16x16x32_f16(a1h[kf], wxl[nt][kf], acc, 0, 0, 0);
        }
#pragma unroll
        for (int c = 0; c < 4; ++c) {
          float v = fast_tanh(acc[c] + bxr[nt]);
          _Float16 vh = (_Float16)v;
          fm_h[kg*4 + c][(pw*4 + nt)*16 + ln] = vh;
          fm_l[kg*4 + c][(pw*4 + nt)*16 + ln] = (_Float16)(v - (float)vh);
        }
      }
    };
    // issue Wih loads for nt in {nt0, nt0+1} (prefetch; consumed next slot)
    auto ld2 = [&](int nt0) {
#pragma unroll
      for (int i = 0; i < 2; ++i) {
        const int ro = (pw*4 + nt0 + i)*16 + ln;
#pragma unroll
        for (int kf = 0; kf < 4; ++kf) {
          const float* wp = Wih + ro*H_DIM + kf*32 + kg*8;
          lw[i*8 + kf*2 + 0] = *(const float4*)wp;
          lw[i*8 + kf*2 + 1] = *(const float4*)(wp + 4);
        }
      }
    };
    // stage2 half: z = feat Wih^T + b2, tri-split (R2-exact arithmetic)
    auto use2 = [&](int nt0, int slot) {
      half8 a2h[4], a2l[4];
#pragma unroll
      for (int kf = 0; kf < 4; ++kf) {
        a2h[kf] = *(const half8*)&fm_h[ln][kf*32 + kg*8];
        a2l[kf] = *(const half8*)&fm_l[ln][kf*32 + kg*8];
      }
#pragma unroll
      for (int i = 0; i < 2; ++i) {
        const int nt = nt0 + i;
        const int ro = (pw*4 + nt)*16 + ln;
        f32x4 acc = { b2r[nt], b2r[nt], b2r[nt], b2r[nt] };
#pragma unroll
        for (int kf = 0; kf < 4; ++kf) {
          half8 bh_, bl_;
          split_h8(lw[i*8 + kf*2], lw[i*8 + kf*2 + 1], bh_, bl_);
          acc = __builtin_amdgcn_mfma_f32_16x16x32_f16(a2h[kf], bh_, acc, 0, 0, 0);
          acc = __builtin_amdgcn_mfma_f32_16x16x32_f16(a2l[kf], bh_, acc, 0, 0, 0);
          acc = __builtin_amdgcn_mfma_f32_16x16x32_f16(a2h[kf], bl_, acc, 0, 0, 0);
        }
        *(f32x4*)&zringT[slot][ro][kg*4] = acc;
      }
    };

    // prologue: granules 0 and 1 (5 barriers) — R2 op order
    loadx(0);
    cvtx(); loadx(16);            barrier_lds_only();   // B1
    st1();                        barrier_lds_only();   // B2
    ld2(0); use2(0, 0); ld2(2); use2(2, 0);
    cvtx(); loadx(32);            barrier_lds_only();   // B3
    st1();                        barrier_lds_only();   // B4
    ld2(0); use2(0, 1); ld2(2); use2(2, 1);
                                  barrier_lds_only();   // B5

    for (int g = 0; g < 64; ++g) {               // produce granule g+2
      const bool act = (g <= 61);
      const int slot = (g + 2) & 3;
      if (act) cvtx();
      if (g <= 60) loadx((g + 3) * 16);
      barrier_lds_only();                        // #1
      if (act) { ld2(0); st1(); }
      barrier_lds_only();                        // #2
      if (act) { use2(0, slot); ld2(2); }
      barrier_lds_only();                        // #3
      if (act) use2(2, slot);
      barrier_lds_only();                        // #4
      for (int s = 4; s < 16; ++s) barrier_lds_only();  // #5..#16
    }
    barrier_lds_only();                          // epilogue

  } else {
    // ===== out consumer (waves 6-7, weight-split f16 MFMA, R2 numerics) ====
    const int l = tid & 63, ln = l & 15, kg = l >> 4;
    const int cw = wv - 6;

    float bhr[4], bgr[2];
#pragma unroll
    for (int nt = 0; nt < 4; ++nt) bhr[nt] = bh[(cw*4 + nt)*16 + ln];
#pragma unroll
    for (int n2 = 0; n2 < 2; ++n2) bgr[n2] = bg[(cw*2 + n2)*16 + ln];

    float4 lwc[16];                      // prefetched Wh/Wg fp32 (64 VGPR)

    // issue Wh loads for nt in {nt0, nt0+1}
    auto ldc1 = [&](int nt0) {
#pragma unroll
      for (int i = 0; i < 2; ++i) {
        const int ro = (cw*4 + nt0 + i)*16 + ln;
#pragma unroll
        for (int kf = 0; kf < 4; ++kf) {
          const float* wp = Wh + ro*H_DIM + kf*32 + kg*8;
          lwc[i*8 + kf*2 + 0] = *(const float4*)wp;
          lwc[i*8 + kf*2 + 1] = *(const float4*)(wp + 4);
        }
      }
    };
    // cstage1 half: tmp = tanh(h Wh^T + bh) (R2-exact)
    auto usec1 = [&](int nt0, int slot) {
      half8 ah[4];
#pragma unroll
      for (int kf = 0; kf < 4; ++kf)
        ah[kf] = *(const half8*)&hring[slot][ln][kf*32 + kg*8];
#pragma unroll
      for (int i = 0; i < 2; ++i) {
        const int nt = nt0 + i;
        f32x4 acc = {0.f, 0.f, 0.f, 0.f};
#pragma unroll
        for (int kf = 0; kf < 4; ++kf) {
          half8 bh_, bl_;
          split_h8(lwc[i*8 + kf*2], lwc[i*8 + kf*2 + 1], bh_, bl_);
          acc = __builtin_amdgcn_mfma_f32_16x16x32_f16(ah[kf], bh_, acc, 0, 0, 0);
          acc = __builtin_amdgcn_mfma_f32_16x16x32_f16(ah[kf], bl_, acc, 0, 0, 0);
        }
#pragma unroll
        for (int c = 0; c < 4; ++c)
          tpm[kg*4 + c][(cw*4 + nt)*16 + ln] =
              (_Float16)fast_tanh(acc[c] + bhr[nt]);
      }
    };
    // issue Wg loads (both n2)
    auto ldc2 = [&]() {
#pragma unroll
      for (int i = 0; i < 2; ++i) {
        const int ro = (cw*2 + i)*16 + ln;
#pragma unroll
        for (int kf = 0; kf < 4; ++kf) {
          const float* wp = Wg + ro*H_DIM + kf*32 + kg*8;
          lwc[i*8 + kf*2 + 0] = *(const float4*)wp;
          lwc[i*8 + kf*2 + 1] = *(const float4*)(wp + 4);
        }
      }
    };
    // cstage2: y = tmp Wg^T + bg (R2-exact)
    auto usec2 = [&](int t0) {
      half8 atp[4];
#pragma unroll
      for (int kf = 0; kf < 4; ++kf)
        atp[kf] = *(const half8*)&tpm[ln][kf*32 + kg*8];
#pragma unroll
      for (int n2 = 0; n2 < 2; ++n2) {
        f32x4 acc = { bgr[n2], bgr[n2], bgr[n2], bgr[n2] };
#pragma unroll
        for (int kf = 0; kf < 4; ++kf) {
          half8 bh_, bl_;
          split_h8(lwc[n2*8 + kf*2], lwc[n2*8 + kf*2 + 1], bh_, bl_);
          acc = __builtin_amdgcn_mfma_f32_16x16x32_f16(atp[kf], bh_, acc, 0, 0, 0);
          acc = __builtin_amdgcn_mfma_f32_16x16x32_f16(atp[kf], bl_, acc, 0, 0, 0);
        }
#pragma unroll
        for (int c = 0; c < 4; ++c)
          y[((long)(t0 + kg*4 + c)*B_SZ + b)*D_IN + (cw*2 + n2)*16 + ln] = acc[c];
      }
    };

    for (int i = 0; i < 5; ++i) barrier_lds_only();        // prologue

    for (int g = 0; g < 64; ++g) {               // consume granule g-1
      const bool act = (g >= 1);
      const int slot = (g - 1) & 3;
      const int t0 = (g - 1) * 16;
      barrier_lds_only();                        // #1
      barrier_lds_only();                        // #2
      barrier_lds_only();                        // #3
      barrier_lds_only();                        // #4
      barrier_lds_only();                        // #5
      barrier_lds_only();                        // #6
      if (act) ldc1(0);
      barrier_lds_only();                        // #7
      if (act) { usec1(0, slot); ldc1(2); }
      barrier_lds_only();                        // #8
      if (act) { usec1(2, slot); ldc2(); }
      barrier_lds_only();                        // #9
      barrier_lds_only();                        // #10
      if (act) usec2(t0);
      barrier_lds_only();                        // #11
      for (int s = 11; s < 16; ++s) barrier_lds_only();  // #12..#16
    }
    // epilogue: granule 63
    ldc1(0); usec1(0, 3); ldc1(2); usec1(2, 3);
    barrier_lds_only();
    ldc2(); usec2(63 * 16);
  }
}

extern "C" void kernel_launch(void* const* d_in, const int* in_sizes, int n_in,
                              void* d_out, int out_size, void* d_ws, size_t ws_size,
                              hipStream_t stream) {
  const float* x   = (const float*)d_in[0];
  const float* Wx  = (const float*)d_in[1];
  const float* bx  = (const float*)d_in[2];
  const float* Wih = (const float*)d_in[3];
  const float* bih = (const float*)d_in[4];
  const float* Whh = (const float*)d_in[5];
  const float* bhh = (const float*)d_in[6];
  const float* Wh  = (const float*)d_in[7];
  const float* bh  = (const float*)d_in[8];
  const float* Wg  = (const float*)d_in[9];
  const float* bg  = (const float*)d_in[10];
  float* y = (float*)d_out;

  k_fused<<<B_SZ, 512, 0, stream>>>(x, Wx, bx, Wih, bih, Whh, bhh,
                                    Wh, bh, Wg, bg, y);
}